// Round 3
// baseline (104.570 us; speedup 1.0000x reference)
//
#include <hip/hip_runtime.h>

// Problem constants
#define N_PIX 4096   // 64*64 pixels
#define N_D   256    // feature dims
#define N_C   19     // classes
#define N_B   51     // bins
#define N_BLOCKS_MAIN (18 * 64)   // k_main grid size (ticket target)

// ws layout (bytes)
#define OFF_LIST   0                      // int  [19][4096]  = 311296 B
#define OFF_COUNTS 311296                 // int  [19]
#define OFF_ACC    311424                 // float[1]
#define OFF_TICKET 311428                 // int[1]

// --- K1: bucket pixel indices by class (blocks 0..18) + feature copy (19..255)
__global__ __launch_bounds__(256) void k_pre(const float* __restrict__ feature,
                                             const int* __restrict__ label,
                                             float* __restrict__ out,
                                             int* __restrict__ list,
                                             int* __restrict__ counts,
                                             float* __restrict__ acc,
                                             int* __restrict__ ticket) {
    const int b = blockIdx.x;
    if (b < N_C) {
        // ---- bucket class b: deterministic 4-wave compaction ----
        const int c = b;
        const int w = threadIdx.x >> 6;
        const int lane = threadIdx.x & 63;
        __shared__ int wcnt[4];
        if (c == 0 && threadIdx.x == 0) { *acc = 0.f; *ticket = 0; }  // ws poisoned

        const int q0 = w * 1024;   // phase 1: count matches in my quarter
        int cnt = 0;
        for (int base = 0; base < 1024; base += 64) {
            cnt += (int)__popcll(__ballot(label[q0 + base + lane] == c));
        }
        if (lane == 0) wcnt[w] = cnt;
        __syncthreads();
        int m = 0;
#pragma unroll
        for (int i = 0; i < 4; ++i) m += (i < w) ? wcnt[i] : 0;

        for (int base = 0; base < 1024; base += 64) {  // phase 2: scatter
            const int n = q0 + base + lane;
            const bool match = (label[n] == c);
            const unsigned long long mask = __ballot(match);
            if (match) list[c * N_PIX + m + __popcll(mask & ((1ull << lane) - 1ull))] = n;
            m += (int)__popcll(mask);
        }
        if (w == 3 && lane == 0) counts[c] = m;
    } else {
        // ---- feature pass-through: out[1..] = feature[0..] ----
        // out+1 is 4B-misaligned for float4 -> float4 loads, scalar stores.
        const int tid = (b - N_C) * 256 + threadIdx.x;
        const int nth = (256 - N_C) * 256;
        const float4* __restrict__ src = (const float4*)feature;
        float* __restrict__ dst = out + 1;
        for (int i = tid; i < N_PIX * N_D / 4; i += nth) {
            const float4 v = src[i];
            dst[4 * i + 0] = v.x;
            dst[4 * i + 1] = v.y;
            dst[4 * i + 2] = v.z;
            dst[4 * i + 3] = v.w;
        }
    }
}

// --- K2 (fused stats + KDE + normalize + smooth-L1 + finalize) ---
// grid = (18, 64), block 256 = 4 waves; wave = one (c,d) row, lane = bin.
// Norm factors 1/sqrt(2*pi*v) cancel after row normalization -> dropped.
__global__ __launch_bounds__(256) void k_main(const float* __restrict__ feature,
                                              const int* __restrict__ list,
                                              const int* __restrict__ counts,
                                              float* __restrict__ acc,
                                              int* __restrict__ ticket,
                                              float* __restrict__ out) {
    const int c = blockIdx.x + 1;                 // class 0 never reaches the loss
    const int w = threadIdx.x >> 6;
    const int d = blockIdx.y * 4 + w;
    const int lane = threadIdx.x & 63;
    const int m = counts[c];
    __shared__ float blk[4];
    float part = 0.f;
    if (m > 0) {
        const float* __restrict__ row = feature + d * N_PIX;  // F[:,d] contiguous
        const int* __restrict__ lst = list + c * N_PIX;

        // -- stats: mean/var via lane-parallel gather + butterfly reduce --
        float s1 = 0.f, s2 = 0.f;
        for (int j = lane; j < m; j += 64) {
            const float f = row[lst[j]];
            s1 += f;
            s2 += f * f;
        }
#pragma unroll
        for (int off = 32; off; off >>= 1) {
            s1 += __shfl_xor(s1, off);
            s2 += __shfl_xor(s2, off);
        }
        const float cnt = (float)m;
        const float mu = s1 / cnt;
        const float v = fmaxf(s2 / cnt - mu * mu, 1e-12f);

        const float LOG2E = 1.44269504088896340736f;
        const float as = -12.5f * LOG2E / v;   // sample kernel: var/25 -> -0.5*25/v
        const float at = -0.5f * LOG2E / v;    // target
        // lanes >= 51: bin=1e18 -> every exp2 arg is -inf -> contributes 0
        const float bin = (lane < N_B) ? fmaf(0.2f, (float)lane, -5.0f) : 1e18f;
        const float tt = bin - mu;
        const float targ = __builtin_amdgcn_exp2f(at * tt * tt);

        // -- KDE: parallel gather of 64 pixels, register broadcast, ILP-4 --
        // tail pad f=-1e18 (NOT +1e18: bin sentinel is +1e18, t would be 0)
        float a0 = 0.f, a1 = 0.f, a2 = 0.f, a3 = 0.f;
        for (int base = 0; base < m; base += 64) {
            const int j = base + lane;
            const float fl = (j < m) ? row[lst[j]] : -1e18f;
#pragma unroll
            for (int k = 0; k < 64; k += 4) {
                const float f0 = __shfl(fl, k);
                const float f1 = __shfl(fl, k + 1);
                const float f2 = __shfl(fl, k + 2);
                const float f3 = __shfl(fl, k + 3);
                const float t0 = f0 - bin, t1 = f1 - bin, t2 = f2 - bin, t3 = f3 - bin;
                a0 += __builtin_amdgcn_exp2f(as * t0 * t0);
                a1 += __builtin_amdgcn_exp2f(as * t1 * t1);
                a2 += __builtin_amdgcn_exp2f(as * t2 * t2);
                a3 += __builtin_amdgcn_exp2f(as * t3 * t3);
            }
        }
        const float acc_s = (a0 + a1) + (a2 + a3);

        // -- row normalize + smooth-L1 --
        float ss = acc_s, st = targ;
#pragma unroll
        for (int off = 32; off; off >>= 1) {
            ss += __shfl_xor(ss, off);
            st += __shfl_xor(st, off);
        }
        const float hist = acc_s / fmaxf(ss, 1e-30f);
        const float tgt  = targ  / fmaxf(st, 1e-30f);
        const float diff = hist - tgt;
        const float ad = fabsf(diff);
        float sl1 = (ad < 1.f) ? 0.5f * diff * diff : ad - 0.5f;
#pragma unroll
        for (int off = 32; off; off >>= 1) sl1 += __shfl_down(sl1, off);
        part = sl1;  // valid on lane 0
    }
    if (lane == 0) blk[w] = part;
    __syncthreads();  // m is block-uniform -> no divergent barrier
    if (threadIdx.x == 0) {
        atomicAdd(acc, blk[0] + blk[1] + blk[2] + blk[3]);
        __threadfence();                       // order acc-add before ticket-add
        const int t = atomicAdd(ticket, 1);    // device-scope
        if (t == N_BLOCKS_MAIN - 1) {          // I'm last: finalize
            int active = 0;
            for (int cc = 1; cc < N_C; ++cc) active += (counts[cc] > 0) ? 1 : 0;
            const float total = atomicAdd(acc, 0.0f);  // coherent read
            out[0] = total / (float)(N_D * N_B) / ((float)active + 1e-12f);
        }
    }
}

extern "C" void kernel_launch(void* const* d_in, const int* in_sizes, int n_in,
                              void* d_out, int out_size, void* d_ws, size_t ws_size,
                              hipStream_t stream) {
    const float* feature = (const float*)d_in[0];   // [1,256,64,64] fp32
    const int* label = (const int*)d_in[1];         // [1,1,64,64] int32
    float* out = (float*)d_out;                     // [0]=loss, [1..]=feature passthrough
    char* ws = (char*)d_ws;
    int* list = (int*)(ws + OFF_LIST);
    int* counts = (int*)(ws + OFF_COUNTS);
    float* acc = (float*)(ws + OFF_ACC);
    int* ticket = (int*)(ws + OFF_TICKET);

    k_pre<<<256, 256, 0, stream>>>(feature, label, out, list, counts, acc, ticket);
    dim3 grid(N_C - 1, N_D / 4);
    k_main<<<grid, 256, 0, stream>>>(feature, list, counts, acc, ticket, out);
}